// Round 1
// 4273.539 us; speedup vs baseline: 1.0567x; 1.0567x over previous
//
#include <hip/hip_runtime.h>
#include <cstdint>
#include <cstddef>

#define B_    64
#define T_    50
#define E_    1024
#define H_    1024
#define NI_   32000
#define KF_   2058   // N + 2H real K of final GEMM
#define KP_   2080   // padded to multiple of 32
#define NW_   10
#define LOUT_ 993.0f

typedef __bf16 bf16_t;
typedef __bf16 bf16x4 __attribute__((ext_vector_type(4)));
typedef __bf16 bf16x8 __attribute__((ext_vector_type(8)));
typedef float  f32x4  __attribute__((ext_vector_type(4)));

#define MFMA16(a,b,c) __builtin_amdgcn_mfma_f32_16x16x32_bf16((a),(b),(c),0,0,0)

typedef const __attribute__((address_space(1))) void* gptr_t;
typedef __attribute__((address_space(3))) void*       lptr_t;

// ---------------- init: zero h0 (f32 slot 0 of hs) and bf16 h buffer ----------
__global__ __launch_bounds__(256) void k_init(float* hs0, bf16_t* h0bf) {
    int i = blockIdx.x * 256 + threadIdx.x;      // 65536 threads
    if (i < B_ * H_) { hs0[i] = 0.f; h0bf[i] = (bf16_t)0.f; }
}

// ---------------- gather embeddings -> Abuf[3200][2048] bf16 ------------------
__global__ __launch_bounds__(256)
void k_gather(const int* __restrict__ uv, const int* __restrict__ iv,
              const float* __restrict__ uemb, const float* __restrict__ iemb,
              bf16_t* __restrict__ Abuf) {
    int row = blockIdx.x;           // b*T + t
    int tid = threadIdx.x;          // 256
    int uid = uv[row], iid = iv[row];
    float4 a = ((const float4*)(uemb + (size_t)uid * E_))[tid];
    float4 b = ((const float4*)(iemb + (size_t)iid * E_))[tid];
    bf16_t* dst = Abuf + (size_t)row * 2048;
    bf16x4 va; va[0]=(bf16_t)a.x; va[1]=(bf16_t)a.y; va[2]=(bf16_t)a.z; va[3]=(bf16_t)a.w;
    bf16x4 vb; vb[0]=(bf16_t)b.x; vb[1]=(bf16_t)b.y; vb[2]=(bf16_t)b.z; vb[3]=(bf16_t)b.w;
    *(bf16x4*)(dst + tid * 4) = va;
    *(bf16x4*)(dst + 1024 + tid * 4) = vb;
}

// ---------------- transpose f32 (K x N) -> bf16 (N x Kout), zero-pad K --------
__global__ __launch_bounds__(256)
void k_transpose_bf16(const float* __restrict__ in, bf16_t* __restrict__ out,
                      int K, int Nn, int Kout) {
    __shared__ float tile[32][33];
    int kb = blockIdx.x * 32, nb = blockIdx.y * 32;
    int tx = threadIdx.x & 31, ty = threadIdx.x >> 5;   // 32 x 8
#pragma unroll
    for (int r = 0; r < 32; r += 8) {
        int k = kb + ty + r, n = nb + tx;
        float v = (k < K && n < Nn) ? in[(size_t)k * Nn + n] : 0.f;
        tile[ty + r][tx] = v;
    }
    __syncthreads();
#pragma unroll
    for (int r = 0; r < 32; r += 8) {
        int n = nb + ty + r, k = kb + tx;
        if (n < Nn && k < Kout) out[(size_t)n * Kout + k] = (bf16_t)tile[tx][ty + r];
    }
}

// ---------------- f32 -> bf16 copy (same layout) ------------------------------
__global__ __launch_bounds__(256)
void k_cvt(const float* __restrict__ in, bf16_t* __restrict__ out, int n) {
    int i = (blockIdx.x * 256 + threadIdx.x) * 4;
    if (i + 3 < n) {
        float4 v = *(const float4*)(in + i);
        bf16x4 o; o[0]=(bf16_t)v.x; o[1]=(bf16_t)v.y; o[2]=(bf16_t)v.z; o[3]=(bf16_t)v.w;
        *(bf16x4*)(out + i) = o;
    }
}

// ---------------- bijective XCD-contiguous block remap (m204 variant) ---------
// Same-B-panel blocks (consecutive m at fixed n) land on one XCD's private L2.
__device__ inline void xcd_remap(int& mblk, int& nblk) {
    int gx = gridDim.x;
    int nwg = gx * gridDim.y;
    int flat = blockIdx.x + gx * blockIdx.y;
    int q = nwg >> 3, r = nwg & 7;
    int xcd = flat & 7, seq = flat >> 3;
    int base = (xcd < r) ? xcd * (q + 1) : r * (q + 1) + (xcd - r) * q;
    int g = base + seq;
    mblk = g % gx;
    nblk = g / gx;
}

// ---------------- 128x128x32 bf16 GEMM (m97 structure) ------------------------
// C = A @ Bt^T + bias (f32 out). A:(M x lda) bf16 K-contig; Bt:(N x ldb) bf16 K-contig.
// Staging: global_load_lds width=16 into LINEAR LDS tiles (Common-mistake #1 fix).
__global__ __launch_bounds__(256)
void k_gemm_bt(const bf16_t* __restrict__ A, int lda,
               const bf16_t* __restrict__ Bt, int ldb,
               const float* __restrict__ bias,
               float* __restrict__ C, int ldc, int K) {
    __shared__ __attribute__((aligned(16))) bf16_t As[128 * 32];
    __shared__ __attribute__((aligned(16))) bf16_t Bs[128 * 32];
    int mblk, nblk;
    xcd_remap(mblk, nblk);
    int m0 = mblk * 128, n0 = nblk * 128;
    int tid = threadIdx.x, lane = tid & 63, wave = tid >> 6;
    int wm = (wave & 1) * 64, wn = (wave >> 1) * 64;
    int quad = lane >> 4, l16 = lane & 15;
    // staging geometry: 8 chunks of 1KB per tile (16 rows x 32 cols bf16 each);
    // wave w owns chunks {2w, 2w+1} of A and of B. Lane l covers bytes [16l,16l+16)
    // of its chunk -> row = c*16 + (l>>2), col elems = (l&3)*8. LDS dest is the
    // wave-uniform chunk base (HW adds lane*16).
    int c0 = wave * 2;
    int srow = lane >> 2, scol = (lane & 3) * 8;
    const bf16_t* gA0 = A  + (size_t)(m0 + c0 * 16      + srow) * lda + scol;
    const bf16_t* gA1 = A  + (size_t)(m0 + c0 * 16 + 16 + srow) * lda + scol;
    const bf16_t* gB0 = Bt + (size_t)(n0 + c0 * 16      + srow) * ldb + scol;
    const bf16_t* gB1 = Bt + (size_t)(n0 + c0 * 16 + 16 + srow) * ldb + scol;
    bf16_t* lA0 = As + c0 * 512;
    bf16_t* lA1 = As + c0 * 512 + 512;
    bf16_t* lB0 = Bs + c0 * 512;
    bf16_t* lB1 = Bs + c0 * 512 + 512;
    f32x4 acc[4][4] = {};
    for (int k0 = 0; k0 < K; k0 += 32) {
        __syncthreads();
        __builtin_amdgcn_global_load_lds((gptr_t)(gA0 + k0), (lptr_t)lA0, 16, 0, 0);
        __builtin_amdgcn_global_load_lds((gptr_t)(gA1 + k0), (lptr_t)lA1, 16, 0, 0);
        __builtin_amdgcn_global_load_lds((gptr_t)(gB0 + k0), (lptr_t)lB0, 16, 0, 0);
        __builtin_amdgcn_global_load_lds((gptr_t)(gB1 + k0), (lptr_t)lB1, 16, 0, 0);
        __syncthreads();   // compiler emits vmcnt(0) drain before s_barrier
        bf16x8 af[4], bf[4];
#pragma unroll
        for (int mt = 0; mt < 4; mt++) af[mt] = *(bf16x8*)&As[(wm + mt * 16 + l16) * 32 + quad * 8];
#pragma unroll
        for (int nt = 0; nt < 4; nt++) bf[nt] = *(bf16x8*)&Bs[(wn + nt * 16 + l16) * 32 + quad * 8];
#pragma unroll
        for (int mt = 0; mt < 4; mt++)
#pragma unroll
            for (int nt = 0; nt < 4; nt++)
                acc[mt][nt] = MFMA16(af[mt], bf[nt], acc[mt][nt]);
    }
#pragma unroll
    for (int mt = 0; mt < 4; mt++)
#pragma unroll
        for (int nt = 0; nt < 4; nt++) {
            int col = n0 + wn + nt * 16 + l16;
            float bv = bias ? bias[col] : 0.f;
#pragma unroll
            for (int r = 0; r < 4; r++) {
                int row = m0 + wm + mt * 16 + quad * 4 + r;
                C[(size_t)row * ldc + col] = acc[mt][nt][r] + bv;
            }
        }
}

// ---------------- per-step: att = sigmoid(att_pre + h@Wh); build x ------------
// grid 64 blocks (16 cols each), K=1024 split over 4 waves
__global__ __launch_bounds__(256)
void k_att_step(const bf16_t* __restrict__ Hcur,   // [64][1024] bf16
                const bf16_t* __restrict__ WhT,    // row n stride ldwh, Wh^T
                int ldwh,
                const float* __restrict__ att_pre, // [3200][1024]
                const bf16_t* __restrict__ Abuf,   // [3200][2048]
                bf16_t* __restrict__ Xb,           // [64][2048] out
                int t) {
    __shared__ float red[4][64][16];
    int tid = threadIdx.x, lane = tid & 63, wave = tid >> 6;
    int quad = lane >> 4, l16 = lane & 15;
    int c0 = blockIdx.x * 16;
    f32x4 acc[4] = {};
    int kbase = wave * 256;
#pragma unroll
    for (int kk = 0; kk < 256; kk += 32) {
        int k = kbase + kk + quad * 8;
        bf16x8 bf = *(const bf16x8*)(WhT + (size_t)(c0 + l16) * ldwh + k);
#pragma unroll
        for (int mt = 0; mt < 4; mt++) {
            bf16x8 af = *(const bf16x8*)(Hcur + (size_t)(mt * 16 + l16) * 1024 + k);
            acc[mt] = MFMA16(af, bf, acc[mt]);
        }
    }
#pragma unroll
    for (int mt = 0; mt < 4; mt++)
#pragma unroll
        for (int r = 0; r < 4; r++)
            red[wave][mt * 16 + quad * 4 + r][l16] = acc[mt][r];
    __syncthreads();
    for (int i = tid; i < 1024; i += 256) {
        int m = i >> 4, c = i & 15;
        float s = red[0][m][c] + red[1][m][c] + red[2][m][c] + red[3][m][c];
        int col = c0 + c;
        int arow = m * T_ + t;
        float att = 1.f / (1.f + __expf(-(att_pre[(size_t)arow * 1024 + col] + s)));
        float uvv = (float)Abuf[(size_t)arow * 2048 + col];
        float ivv = (float)Abuf[(size_t)arow * 2048 + 1024 + col];
        Xb[(size_t)m * 2048 + col] = (bf16_t)(att * uvv);
        Xb[(size_t)m * 2048 + 1024 + col] = (bf16_t)((1.f - att) * ivv);
    }
}

// ---------------- per-step: gates + GRU update --------------------------------
// grid 64 blocks (16 gate-cols each). wave0/1: r,z over x halves; wave2: r,z over h;
// wave3: gi_n over x + gh_n over h. LDS reduce, fused epilogue.
__global__ __launch_bounds__(256)
void k_gates_step(const bf16_t* __restrict__ Xb,    // [64][2048]
                  const bf16_t* __restrict__ Hcur,  // [64][1024] bf16
                  const bf16_t* __restrict__ Wih,   // [3072][2048] bf16
                  const bf16_t* __restrict__ Whh,   // [3072][1024] bf16
                  const float* __restrict__ b_ih, const float* __restrict__ b_hh,
                  const float* __restrict__ hprev,  // [64][1024] f32 (h_{t-1})
                  float* __restrict__ hout,         // [64][1024] f32 (h_t)
                  bf16_t* __restrict__ Hnxt) {      // [64][1024] bf16
    __shared__ float red[8][64][16];  // 0-2:R 3-5:Z 6:NI 7:NH
    int tid = threadIdx.x, lane = tid & 63, wave = tid >> 6;
    int quad = lane >> 4, l16 = lane & 15;
    int c0 = blockIdx.x * 16;
    f32x4 a0[4] = {}, a1[4] = {};
    int s0, s1;
    if (wave < 2) {
        int kb = wave * 1024;
#pragma unroll 4
        for (int kk = 0; kk < 1024; kk += 32) {
            int k = kb + kk + quad * 8;
            bf16x8 br = *(const bf16x8*)(Wih + (size_t)(c0 + l16) * 2048 + k);
            bf16x8 bz = *(const bf16x8*)(Wih + (size_t)(1024 + c0 + l16) * 2048 + k);
#pragma unroll
            for (int mt = 0; mt < 4; mt++) {
                bf16x8 af = *(const bf16x8*)(Xb + (size_t)(mt * 16 + l16) * 2048 + k);
                a0[mt] = MFMA16(af, br, a0[mt]);
                a1[mt] = MFMA16(af, bz, a1[mt]);
            }
        }
        s0 = wave; s1 = 3 + wave;
    } else if (wave == 2) {
#pragma unroll 4
        for (int kk = 0; kk < 1024; kk += 32) {
            int k = kk + quad * 8;
            bf16x8 br = *(const bf16x8*)(Whh + (size_t)(c0 + l16) * 1024 + k);
            bf16x8 bz = *(const bf16x8*)(Whh + (size_t)(1024 + c0 + l16) * 1024 + k);
#pragma unroll
            for (int mt = 0; mt < 4; mt++) {
                bf16x8 af = *(const bf16x8*)(Hcur + (size_t)(mt * 16 + l16) * 1024 + k);
                a0[mt] = MFMA16(af, br, a0[mt]);
                a1[mt] = MFMA16(af, bz, a1[mt]);
            }
        }
        s0 = 2; s1 = 5;
    } else {
#pragma unroll 4
        for (int kk = 0; kk < 2048; kk += 32) {
            int k = kk + quad * 8;
            bf16x8 bn = *(const bf16x8*)(Wih + (size_t)(2048 + c0 + l16) * 2048 + k);
#pragma unroll
            for (int mt = 0; mt < 4; mt++) {
                bf16x8 af = *(const bf16x8*)(Xb + (size_t)(mt * 16 + l16) * 2048 + k);
                a0[mt] = MFMA16(af, bn, a0[mt]);
            }
        }
#pragma unroll 4
        for (int kk = 0; kk < 1024; kk += 32) {
            int k = kk + quad * 8;
            bf16x8 bn = *(const bf16x8*)(Whh + (size_t)(2048 + c0 + l16) * 1024 + k);
#pragma unroll
            for (int mt = 0; mt < 4; mt++) {
                bf16x8 af = *(const bf16x8*)(Hcur + (size_t)(mt * 16 + l16) * 1024 + k);
                a1[mt] = MFMA16(af, bn, a1[mt]);
            }
        }
        s0 = 6; s1 = 7;
    }
#pragma unroll
    for (int mt = 0; mt < 4; mt++)
#pragma unroll
        for (int r = 0; r < 4; r++) {
            red[s0][mt * 16 + quad * 4 + r][l16] = a0[mt][r];
            red[s1][mt * 16 + quad * 4 + r][l16] = a1[mt][r];
        }
    __syncthreads();
    for (int i = tid; i < 1024; i += 256) {
        int m = i >> 4, c = i & 15;
        int gc = c0 + c;
        float rsum = red[0][m][c] + red[1][m][c] + red[2][m][c] + b_ih[gc] + b_hh[gc];
        float zsum = red[3][m][c] + red[4][m][c] + red[5][m][c] + b_ih[1024 + gc] + b_hh[1024 + gc];
        float gin = red[6][m][c] + b_ih[2048 + gc];
        float ghn = red[7][m][c] + b_hh[2048 + gc];
        float rr = 1.f / (1.f + __expf(-rsum));
        float zz = 1.f / (1.f + __expf(-zsum));
        float nn = tanhf(gin + rr * ghn);
        float hold = hprev[(size_t)m * 1024 + gc];
        float hnew = (1.f - zz) * nn + zz * hold;
        hout[(size_t)m * 1024 + gc] = hnew;
        Hnxt[(size_t)m * 1024 + gc] = (bf16_t)hnew;
    }
}

// ---------------- post: build ful[3200][2080] = [v(10) | h(1024) | l(1024) | 0] ----
__global__ __launch_bounds__(256)
void k_post(const float* __restrict__ hs,   // [51][64][1024], slot t+1 = h_t
            const float* __restrict__ hcovW, const float* __restrict__ hcovb,
            const float* __restrict__ vcovW, const float* __restrict__ vcovb,
            bf16_t* __restrict__ ful) {
    int row = blockIdx.x;               // b*T + t
    int b = row / T_, t = row % T_;
    const float* h = hs + ((size_t)(t + 1) * 64 + b) * 1024;
    __shared__ float sh[1024];
    __shared__ float wsum[4];
    __shared__ float cs[32];
    int tid = threadIdx.x;
    float4 hv = ((const float4*)h)[tid];
    sh[tid * 4 + 0] = hv.x; sh[tid * 4 + 1] = hv.y;
    sh[tid * 4 + 2] = hv.z; sh[tid * 4 + 3] = hv.w;
    float local = hv.x + hv.y + hv.z + hv.w;
#pragma unroll
    for (int off = 32; off; off >>= 1) local += __shfl_down(local, off);
    if ((tid & 63) == 0) wsum[tid >> 6] = local;
    __syncthreads();
    float total = wsum[0] + wsum[1] + wsum[2] + wsum[3];
    if (tid < 32) {
        float p = 0.f;
        for (int i = 0; i < tid; i++) p += sh[i];
        float s = 0.f;
        for (int i = 993 + tid; i < 1024; i++) s += sh[i];
        cs[tid] = total - p - s;   // sliding window sum h[tid .. tid+992]
    }
    __syncthreads();
    bf16_t* outr = ful + (size_t)row * KP_;
    if (tid < NW_) {
        float v = hcovb[tid] * LOUT_;
        for (int j = 0; j < 32; j++) v += cs[j] * hcovW[tid * 32 + j];
        outr[tid] = (bf16_t)v;
    }
    if (tid < (KP_ - KF_)) outr[KF_ + tid] = (bf16_t)0.f;
    float vb = vcovb[0];
    for (int i = tid; i < 1024; i += 256) {
        float hh = sh[i];
        outr[NW_ + i] = (bf16_t)hh;
        float l = 0.f;
        if (t >= 3) {
            float q = vb;
#pragma unroll
            for (int c = 0; c < 4; c++)
                q += vcovW[c] * hs[((size_t)(t - 3 + c + 1) * 64 + b) * 1024 + i];
            l = hh * q;
        }
        outr[NW_ + 1024 + i] = (bf16_t)l;
    }
}

// ---------------- in-place log-softmax, ONLINE max+sum (2 passes not 3) -------
__global__ __launch_bounds__(256)
void k_logsoftmax(float* __restrict__ logits) {
    int row = blockIdx.x;
    float* p = logits + (size_t)row * NI_;
    int tid = threadIdx.x;
    __shared__ float redm[4], reds[4];
    float m = -1e30f, s = 0.f;
    for (int c = tid; c < NI_ / 4; c += 256) {
        float4 v = ((const float4*)p)[c];
        float m4 = fmaxf(fmaxf(v.x, v.y), fmaxf(v.z, v.w));
        if (m4 > m) { s *= __expf(m - m4); m = m4; }
        s += __expf(v.x - m) + __expf(v.y - m) + __expf(v.z - m) + __expf(v.w - m);
    }
#pragma unroll
    for (int off = 32; off; off >>= 1) {
        float mo = __shfl_down(m, off), so = __shfl_down(s, off);
        float mn = fmaxf(m, mo);
        s = s * __expf(m - mn) + so * __expf(mo - mn);
        m = mn;
    }
    if ((tid & 63) == 0) { redm[tid >> 6] = m; reds[tid >> 6] = s; }
    __syncthreads();
    float M = fmaxf(fmaxf(redm[0], redm[1]), fmaxf(redm[2], redm[3]));
    float S = reds[0] * __expf(redm[0] - M) + reds[1] * __expf(redm[1] - M) +
              reds[2] * __expf(redm[2] - M) + reds[3] * __expf(redm[3] - M);
    float lse = M + __logf(S);
    for (int c = tid; c < NI_ / 4; c += 256) {
        float4 v = ((const float4*)p)[c];
        v.x -= lse; v.y -= lse; v.z -= lse; v.w -= lse;
        ((float4*)p)[c] = v;
    }
}

extern "C" void kernel_launch(void* const* d_in, const int* in_sizes, int n_in,
                              void* d_out, int out_size, void* d_ws, size_t ws_size,
                              hipStream_t stream) {
    const int*   uv    = (const int*)d_in[0];
    const int*   iv    = (const int*)d_in[1];
    const float* uemb  = (const float*)d_in[2];
    const float* iemb  = (const float*)d_in[3];
    const float* attW  = (const float*)d_in[4];
    const float* attb  = (const float*)d_in[5];
    const float* Wih   = (const float*)d_in[6];
    const float* bih   = (const float*)d_in[7];
    const float* Whh   = (const float*)d_in[8];
    const float* bhh   = (const float*)d_in[9];
    const float* hcovW = (const float*)d_in[10];
    const float* hcovb = (const float*)d_in[11];
    const float* vcovW = (const float*)d_in[12];
    const float* vcovb = (const float*)d_in[13];
    const float* linW  = (const float*)d_in[14];
    const float* linb  = (const float*)d_in[15];
    float* out = (float*)d_out;

    char* p = (char*)d_ws;
    auto alloc = [&](size_t bytes) { void* r = (void*)p; p += (bytes + 255) & ~(size_t)255; return r; };
    bf16_t* Abuf   = (bf16_t*)alloc((size_t)3200 * 2048 * 2);   // [b*T+t][u|it]
    float*  attpre = (float*) alloc((size_t)3200 * 1024 * 4);
    bf16_t* attWt  = (bf16_t*)alloc((size_t)1024 * 3072 * 2);   // attW^T
    bf16_t* WihB   = (bf16_t*)alloc((size_t)3072 * 2048 * 2);
    bf16_t* WhhB   = (bf16_t*)alloc((size_t)3072 * 1024 * 2);
    bf16_t* linWt  = (bf16_t*)alloc((size_t)32000 * KP_ * 2);   // lin_W^T, K-padded
    bf16_t* fulB   = (bf16_t*)alloc((size_t)3200 * KP_ * 2);
    float*  hsB    = (float*) alloc((size_t)51 * 64 * 1024 * 4); // slot0 = h_{-1} = 0
    bf16_t* Xb     = (bf16_t*)alloc((size_t)64 * 2048 * 2);
    bf16_t* Hbf    = (bf16_t*)alloc((size_t)2 * 64 * 1024 * 2);  // ping-pong h bf16

    // init zeros (ws is poisoned before every call)
    k_init<<<256, 256, 0, stream>>>(hsB, Hbf);
    // gather embeddings
    k_gather<<<3200, 256, 0, stream>>>(uv, iv, uemb, iemb, Abuf);
    // weight conversions
    k_transpose_bf16<<<dim3(96, 32), 256, 0, stream>>>(attW, attWt, 3072, 1024, 3072);
    k_transpose_bf16<<<dim3(65, 1000), 256, 0, stream>>>(linW, linWt, KF_, NI_, KP_);
    k_cvt<<<6144, 256, 0, stream>>>(Wih, WihB, 3072 * 2048);
    k_cvt<<<3072, 256, 0, stream>>>(Whh, WhhB, 3072 * 1024);
    // att_pre = [u|it] @ attW[0:2048] + att_b
    k_gemm_bt<<<dim3(25, 8), 256, 0, stream>>>(Abuf, 2048, attWt, 3072, attb, attpre, 1024, 2048);
    // recurrence
    bf16_t* Hcur = Hbf;
    bf16_t* Hnxt = Hbf + 64 * 1024;
    for (int t = 0; t < T_; t++) {
        k_att_step<<<64, 256, 0, stream>>>(Hcur, attWt + 2048, 3072, attpre, Abuf, Xb, t);
        k_gates_step<<<64, 256, 0, stream>>>(Xb, Hcur, WihB, WhhB, bih, bhh,
                                             hsB + (size_t)t * 65536,
                                             hsB + (size_t)(t + 1) * 65536, Hnxt);
        bf16_t* tmp = Hcur; Hcur = Hnxt; Hnxt = tmp;
    }
    // v / h / l -> ful
    k_post<<<3200, 256, 0, stream>>>(hsB, hcovW, hcovb, vcovW, vcovb, fulB);
    // logits = ful @ lin_W + lin_b
    k_gemm_bt<<<dim3(25, 250), 256, 0, stream>>>(fulB, KP_, linWt, KP_, linb, out, NI_, KP_);
    // in-place log-softmax
    k_logsoftmax<<<3200, 256, 0, stream>>>(out);
}